// Round 7
// baseline (142.936 us; speedup 1.0000x reference)
//
#include <hip/hip_runtime.h>

typedef __attribute__((ext_vector_type(8))) short short8;
typedef __attribute__((ext_vector_type(4))) short short4v;
typedef __attribute__((ext_vector_type(4))) float f32x4;

__device__ __forceinline__ short f2bf(float f) {
  unsigned u = __builtin_bit_cast(unsigned, f);
  u = u + 0x7fffu + ((u >> 16) & 1u);
  return (short)(u >> 16);
}
__device__ __forceinline__ float bf2f(short s) {
  unsigned u = ((unsigned)(unsigned short)s) << 16;
  return __builtin_bit_cast(float, u);
}

// ---------------- fused: gn_stats + weight cast + lsum zero
__global__ __launch_bounds__(256) void pre_kernel(
    const float* __restrict__ x, float2* __restrict__ part,
    const float* __restrict__ wq, const float* __restrict__ wk,
    const float* __restrict__ wv, const float* __restrict__ wp,
    short* __restrict__ wout, float* __restrict__ lz) {
  const int blk = blockIdx.x, t = threadIdx.x;
  if (blk < 1024) {
    const float* base = x + (long)blk * 8192;
    float s = 0.f, ss = 0.f;
#pragma unroll
    for (int j = 0; j < 8; ++j) {
      float4 v = ((const float4*)base)[t + j * 256];
      s  += v.x + v.y + v.z + v.w;
      ss += v.x * v.x + v.y * v.y + v.z * v.z + v.w * v.w;
    }
    for (int o = 32; o > 0; o >>= 1) { s += __shfl_xor(s, o, 64); ss += __shfl_xor(ss, o, 64); }
    __shared__ float rs[4], rss[4];
    if ((t & 63) == 0) { rs[t >> 6] = s; rss[t >> 6] = ss; }
    __syncthreads();
    if (t == 0) {
      part[blk] = make_float2(rs[0] + rs[1] + rs[2] + rs[3],
                              rss[0] + rss[1] + rss[2] + rss[3]);
    }
  } else if (blk < 2048) {
    int i = (blk - 1024) * 256 + t;
    wout[i]          = f2bf(wq[i]);
    wout[262144 + i] = f2bf(wk[i]);
    wout[524288 + i] = f2bf(wv[i]);
    wout[786432 + i] = f2bf(wp[i]);
  } else {
    float4* p = (float4*)lz;
    const int base = (blk - 2048) * 1024 + t * 4;
#pragma unroll
    for (int k = 0; k < 4; ++k) p[base + k] = make_float4(0.f, 0.f, 0.f, 0.f);
  }
}

// ---------------- GN pass 2: normalize + transpose to xnt[B,N,C]
#define TP 133
__global__ __launch_bounds__(256) void gn_norm_t(
    const float* __restrict__ x, const float2* __restrict__ part,
    const float* __restrict__ gamma, const float* __restrict__ beta,
    short* __restrict__ xnt) {
  const int blk = blockIdx.x;
  const int nc = blk & 7, g = (blk >> 3) & 7, b = blk >> 6;
  const int t = threadIdx.x;
  float s = 0.f, ss = 0.f;
#pragma unroll
  for (int j = 0; j < 8; ++j) {
    float2 p = part[(b * 8 + g) * 8 + j];
    s += p.x; ss += p.y;
  }
  const float mean = s * (1.f / 65536.f);
  const float var  = ss * (1.f / 65536.f) - mean * mean;
  const float rstd = rsqrtf(var + 1e-5f);

  const float* base = x + (long)(b * 512 + g * 64) * 1024 + nc * 128;
  __shared__ float tile[64][TP];
  const int row = t >> 2, c4 = t & 3;
#pragma unroll
  for (int j = 0; j < 8; ++j) {
    float4 v = *(const float4*)(base + (long)row * 1024 + (c4 + j * 4) * 4);
    *(float4*)&tile[row][(c4 + j * 4) * 4] = v;
  }
  const int cl4 = (t & 15) * 4;
  float ga[4], be[4];
#pragma unroll
  for (int j = 0; j < 4; ++j) {
    float gm = gamma[g * 64 + cl4 + j];
    ga[j] = gm * rstd;
    be[j] = beta[g * 64 + cl4 + j] - mean * ga[j];
  }
  __syncthreads();
  short* outb = xnt + (long)b * 524288 + (long)(nc * 128) * 512 + g * 64 + cl4;
#pragma unroll
  for (int it = 0; it < 8; ++it) {
    const int tok = (t >> 4) + it * 16;
    short4v o;
    o.x = f2bf(tile[cl4 + 0][tok] * ga[0] + be[0]);
    o.y = f2bf(tile[cl4 + 1][tok] * ga[1] + be[1]);
    o.z = f2bf(tile[cl4 + 2][tok] * ga[2] + be[2]);
    o.w = f2bf(tile[cl4 + 3][tok] * ga[3] + be[3]);
    *(short4v*)(outb + (long)tok * 512) = o;
  }
}

// ================ 256x256 BK=32 4-slot pipelined GEMM core (512 thr, 8 waves)
// C[M,N] = A[M,K]*Bt[N,K]^T bf16. Wave-tile 128x64 (2Mx4N wave grid).
// LDS: 4 K-slice slots x {A[256][32], B[256][32]} = 128 KiB. Depth-3 prefetch,
// counted vmcnt(8) steady state, ONE s_barrier per K-step.
__device__ __forceinline__ int swz32(int r, int g) {  // row r, 16B-granule g(0..3)
  const int sr = r >> 1;
  const int pg = (((r & 1) << 2) | g) ^ (sr & 7);
  return sr * 64 + pg * 8;
}

__device__ __forceinline__ void stage_ab(
    const short* __restrict__ Ab, const short* __restrict__ Bb,
    short* lds, int slot, int m0, int n0, int K, long k0, int tid) {
#pragma unroll
  for (int l = 0; l < 2; ++l) {
    const int gi = l * 512 + tid;
    const int sr = gi >> 3, ps = gi & 7;
    const int lg = ps ^ (sr & 7);
    const int r = sr * 2 + (lg >> 2);
    const int g = lg & 3;
    __builtin_amdgcn_global_load_lds(
        (const __attribute__((address_space(1))) void*)(Ab + (long)(m0 + r) * K + k0 + g * 8),
        (__attribute__((address_space(3))) void*)(lds + slot * 8192 + gi * 8), 16, 0, 0);
    __builtin_amdgcn_global_load_lds(
        (const __attribute__((address_space(1))) void*)(Bb + (long)(n0 + r) * K + k0 + g * 8),
        (__attribute__((address_space(3))) void*)(lds + 32768 + slot * 8192 + gi * 8), 16, 0, 0);
  }
}

__device__ __forceinline__ void gemm_core_256(
    const short* __restrict__ Ab, const short* __restrict__ Bb,
    short* lds, f32x4 (&acc)[8][4], int m0, int n0, int K, int tid) {
  const int lane = tid & 63, w = tid >> 6;
  const int wm = (w >> 2) * 128, wn = (w & 3) * 64;
  const int g = lane >> 4, ar = lane & 15;
  const int NT = K >> 5;
  stage_ab(Ab, Bb, lds, 0, m0, n0, K, 0, tid);
  stage_ab(Ab, Bb, lds, 1, m0, n0, K, 32, tid);
  stage_ab(Ab, Bb, lds, 2, m0, n0, K, 64, tid);
  for (int h = 0; h < NT; ++h) {
    // slot h's 4 loads are (pending+1..pending+4)-oldest; younger: <=2 stages.
    if (h < NT - 2)       { asm volatile("s_waitcnt vmcnt(8)" ::: "memory"); }
    else if (h == NT - 2) { asm volatile("s_waitcnt vmcnt(4)" ::: "memory"); }
    else                  { asm volatile("s_waitcnt vmcnt(0)" ::: "memory"); }
    __builtin_amdgcn_sched_barrier(0);
    __builtin_amdgcn_s_barrier();
    __builtin_amdgcn_sched_barrier(0);
    if (h + 3 < NT)
      stage_ab(Ab, Bb, lds, (h + 3) & 3, m0, n0, K, (long)(h + 3) * 32, tid);
    const short* As = lds + (h & 3) * 8192;
    const short* Bs = lds + 32768 + (h & 3) * 8192;
    short8 af[8], bfv[4];
#pragma unroll
    for (int j = 0; j < 4; ++j)
      bfv[j] = *(const short8*)(Bs + swz32(wn + j * 16 + ar, g));
#pragma unroll
    for (int i = 0; i < 8; ++i)
      af[i] = *(const short8*)(As + swz32(wm + i * 16 + ar, g));
    __builtin_amdgcn_s_setprio(1);
#pragma unroll
    for (int i = 0; i < 8; ++i)
#pragma unroll
      for (int j = 0; j < 4; ++j)
        acc[i][j] = __builtin_amdgcn_mfma_f32_16x16x32_bf16(af[i], bfv[j], acc[i][j], 0, 0, 0);
    __builtin_amdgcn_s_setprio(0);
  }
}

// ---------------- fused QKV projection GEMM (256-tile core)
// W stacked [wq;wk;wv]=[1536,512]. grid (4, 6, 16): y -> m-tile (256 rows).
__global__ __launch_bounds__(512, 2) void qkv_gemm(
    const short* __restrict__ W, const short* __restrict__ xnt,
    short* __restrict__ q_t, short* __restrict__ k_t, short* __restrict__ vbf,
    const float* __restrict__ bq, const float* __restrict__ bk,
    const float* __restrict__ bv) {
  __shared__ short lds[65536];
  const int b = blockIdx.z, y = blockIdx.y;
  const int m0 = y * 256, n0 = blockIdx.x * 256;
  const int which = m0 >> 9;            // 0=q, 1=k, 2=v (256 | 512 boundaries)
  const int mloc0 = m0 - which * 512;
  const short* Bb = xnt + (long)b * 524288;
  const int tid = threadIdx.x, lane = tid & 63, w = tid >> 6;
  f32x4 acc[8][4] = {};
  gemm_core_256(W, Bb, lds, acc, m0, n0, 512, tid);

  const int wm = (w >> 2) * 128, wn = (w & 3) * 64;
  const int mb = mloc0 + wm + (lane >> 4) * 4;
  const int nb = n0 + wn + (lane & 15);
  if (which < 2) {
    short* C = (which ? k_t : q_t) + (long)b * 524288;
    const float* bias = which ? bk : bq;
#pragma unroll
    for (int i = 0; i < 8; ++i) {
      int m = mb + i * 16;
      float b0 = bias[m], b1 = bias[m + 1], b2 = bias[m + 2], b3 = bias[m + 3];
#pragma unroll
      for (int j = 0; j < 4; ++j) {
        int n = nb + j * 16;
        short4v o;
        o.x = f2bf(acc[i][j][0] + b0);
        o.y = f2bf(acc[i][j][1] + b1);
        o.z = f2bf(acc[i][j][2] + b2);
        o.w = f2bf(acc[i][j][3] + b3);
        *(short4v*)(C + (long)n * 512 + m) = o;  // [tok][ch]
      }
    }
  } else {
    short* C = vbf + (long)b * 524288;  // [ch][tok]
#pragma unroll
    for (int i = 0; i < 8; ++i) {
#pragma unroll
      for (int r = 0; r < 4; ++r) {
        int m = mb + i * 16 + r;
        float bi = bv[m];
#pragma unroll
        for (int j = 0; j < 4; ++j) {
          int n = nb + j * 16;
          C[(long)m * 1024 + n] = f2bf(acc[i][j][r] + bi);
        }
      }
    }
  }
}

// ---------------- S = exp(K.Q^T * scale) with rowsum atomics (256-tile core)
__global__ __launch_bounds__(512, 2) void sexp_gemm(
    const short* __restrict__ k_t, const short* __restrict__ q_t,
    short* __restrict__ S, float* __restrict__ lsum, float scale) {
  __shared__ short lds[65536];
  const int b = blockIdx.z;
  const int m0 = blockIdx.y * 256, n0 = blockIdx.x * 256;
  const short* Ab = k_t + (long)b * 524288;
  const short* Bb = q_t + (long)b * 524288;
  const int tid = threadIdx.x, lane = tid & 63, w = tid >> 6;
  f32x4 acc[8][4] = {};
  gemm_core_256(Ab, Bb, lds, acc, m0, n0, 512, tid);

  const int wm = (w >> 2) * 128, wn = (w & 3) * 64;
  const int mb = m0 + wm + (lane >> 4) * 4;   // key
  const int nb = n0 + wn + (lane & 15);       // query
  short* C = S + (long)b * 1048576;
  float rowsum[4] = {0.f, 0.f, 0.f, 0.f};
#pragma unroll
  for (int j = 0; j < 4; ++j) {
    int n = nb + j * 16;
#pragma unroll
    for (int i = 0; i < 8; ++i) {
      int m = mb + i * 16;
      float e0 = __expf(acc[i][j][0] * scale);
      float e1 = __expf(acc[i][j][1] * scale);
      float e2 = __expf(acc[i][j][2] * scale);
      float e3 = __expf(acc[i][j][3] * scale);
      rowsum[j] += (e0 + e1) + (e2 + e3);
      short4v o;
      o.x = f2bf(e0); o.y = f2bf(e1); o.z = f2bf(e2); o.w = f2bf(e3);
      *(short4v*)(C + (long)n * 1024 + m) = o;  // P'[q][key]
    }
  }
#pragma unroll
  for (int j = 0; j < 4; ++j) {
    rowsum[j] += __shfl_xor(rowsum[j], 16, 64);
    rowsum[j] += __shfl_xor(rowsum[j], 32, 64);
  }
  if (lane < 16) {
#pragma unroll
    for (int j = 0; j < 4; ++j)
      atomicAdd(&lsum[b * 1024 + nb + j * 16], rowsum[j]);
  }
}

// ================ 128x128 2-barrier core (proven) for PV / proj
#define BM 128
#define BK 64
enum { EPI_PV = 4, EPI_RES_F32 = 2 };

__device__ __forceinline__ int swz_idx(int row, int k) {
  return row * 64 + ((((k >> 3) ^ row) & 7) << 3) + (k & 7);
}

__device__ __forceinline__ void gemm_core(
    const short* __restrict__ Ab, const short* __restrict__ Bb,
    short* lds, f32x4 (&acc)[4][4], int m0, int n0, int K, int tid) {
  const int lane = tid & 63, w = tid >> 6;
  const int wm = (w >> 1) * 64, wn = (w & 1) * 64;
  const int rowst = w * 32 + (lane >> 3);
  for (int k0 = 0; k0 < K; k0 += BK) {
    __syncthreads();
#pragma unroll
    for (int it = 0; it < 4; ++it) {
      int ci = w * 4 + it;
      int row = rowst + it * 8;
      int slot = (lane & 7) ^ (row & 7);
      const short* ga = Ab + (long)(m0 + row) * K + k0 + slot * 8;
      __builtin_amdgcn_global_load_lds(
          (const __attribute__((address_space(1))) void*)ga,
          (__attribute__((address_space(3))) void*)(lds + ci * 512), 16, 0, 0);
      const short* gb = Bb + (long)(n0 + row) * K + k0 + slot * 8;
      __builtin_amdgcn_global_load_lds(
          (const __attribute__((address_space(1))) void*)gb,
          (__attribute__((address_space(3))) void*)(lds + 8192 + ci * 512), 16, 0, 0);
    }
    __syncthreads();
#pragma unroll
    for (int kk = 0; kk < 2; ++kk) {
      short8 af[4], bf[4];
      const int kf = kk * 32 + (lane >> 4) * 8;
#pragma unroll
      for (int i = 0; i < 4; ++i) {
        af[i] = *(const short8*)(lds + swz_idx(wm + i * 16 + (lane & 15), kf));
        bf[i] = *(const short8*)(lds + 8192 + swz_idx(wn + i * 16 + (lane & 15), kf));
      }
#pragma unroll
      for (int i = 0; i < 4; ++i)
#pragma unroll
        for (int j = 0; j < 4; ++j)
          acc[i][j] = __builtin_amdgcn_mfma_f32_16x16x32_bf16(af[i], bf[j], acc[i][j], 0, 0, 0);
    }
  }
}

template <int EPI>
__global__ __launch_bounds__(256, 3) void gemm_bt(
    const short* __restrict__ A, const short* __restrict__ Bt,
    void* __restrict__ Cv, const float* __restrict__ bias,
    const float* __restrict__ resid, float scale,
    int M, int N, int K, long aStr, long bStr, long cStr, long rStr,
    float* __restrict__ lsum) {
  __shared__ short lds[2 * BM * BK];
  const int b = blockIdx.z;
  const short* Ab = A + (long)b * aStr;
  const short* Bb = Bt + (long)b * bStr;
  const int m0 = blockIdx.y * BM, n0 = blockIdx.x * BM;
  const int tid = threadIdx.x, lane = tid & 63, w = tid >> 6;
  f32x4 acc[4][4] = {};
  gemm_core(Ab, Bb, lds, acc, m0, n0, K, tid);

  const int wm = (w >> 1) * 64, wn = (w & 1) * 64;
  const int mb = m0 + wm + (lane >> 4) * 4;
  const int nb = n0 + wn + (lane & 15);
  if constexpr (EPI == EPI_PV) {
    // A=P'[q][key], Bt=v[ch][key]. h[q][ch] = acc / lsum[b][q].
    short* C = (short*)Cv + (long)b * cStr;
#pragma unroll
    for (int i = 0; i < 4; ++i) {
#pragma unroll
      for (int r = 0; r < 4; ++r) {
        int m = mb + i * 16 + r;  // query
        float rl = 1.0f / lsum[b * 1024 + m];
#pragma unroll
        for (int j = 0; j < 4; ++j) {
          int n = nb + j * 16;  // channel
          C[(long)m * N + n] = f2bf(acc[i][j][r] * rl);
        }
      }
    }
  } else {  // EPI_RES_F32
    float* C = (float*)Cv + (long)b * cStr;
    const float* R = resid + (long)b * rStr;
#pragma unroll
    for (int i = 0; i < 4; ++i) {
#pragma unroll
      for (int r = 0; r < 4; ++r) {
        int m = mb + i * 16 + r;
        float bi = bias[m];
#pragma unroll
        for (int j = 0; j < 4; ++j) {
          int n = nb + j * 16;
          C[(long)m * N + n] = acc[i][j][r] + bi + R[(long)m * N + n];
        }
      }
    }
  }
}

// ---------------------------------------------------------------- launch
extern "C" void kernel_launch(void* const* d_in, const int* in_sizes, int n_in,
                              void* d_out, int out_size, void* d_ws, size_t ws_size,
                              hipStream_t stream) {
  const float* x     = (const float*)d_in[0];
  const float* gamma = (const float*)d_in[1];
  const float* beta  = (const float*)d_in[2];
  const float* wq    = (const float*)d_in[3];
  const float* bq    = (const float*)d_in[4];
  const float* wk    = (const float*)d_in[5];
  const float* bk    = (const float*)d_in[6];
  const float* wv    = (const float*)d_in[7];
  const float* bv    = (const float*)d_in[8];
  const float* wp    = (const float*)d_in[9];
  const float* bp    = (const float*)d_in[10];

  char* ws = (char*)d_ws;
  short* wbf = (short*)ws;                       // [wq;wk;wv;wp] bf16, 2 MB
  short* xnt = (short*)(ws + 2097152l);          // [B,N,C] bf16, 16 MB
  short* q_t = (short*)(ws + 18874368l);         // [B,tok,ch]
  short* k_t = (short*)(ws + 35651584l);         // [B,tok,ch]
  short* vbf = (short*)(ws + 52428800l);         // [B,ch,tok]
  short* Sbf = (short*)(ws + 69206016l);         // [B,N,N] bf16 (P')
  short* h_t = xnt;                              // alias (xn dead after qkv)
  float2* gnpart = (float2*)Sbf;                 // 8 KB, dead before S written
  float* lsum = (float*)d_out;                   // 64 KB; proj overwrites later

  pre_kernel<<<2052, 256, 0, stream>>>(x, gnpart, wq, wk, wv, wp, wbf, lsum);
  gn_norm_t<<<1024, 256, 0, stream>>>(x, gnpart, gamma, beta, xnt);

  qkv_gemm<<<dim3(4, 6, 16), 512, 0, stream>>>(
      wbf, xnt, q_t, k_t, vbf, bq, bk, bv);

  const float iscale = 0.044194173824159216f;  // 1/sqrt(512)
  sexp_gemm<<<dim3(4, 4, 16), 512, 0, stream>>>(k_t, q_t, Sbf, lsum, iscale);

  // h_t[q][ch] = (P' . v^T) / lsum[q]
  gemm_bt<EPI_PV><<<dim3(4, 8, 16), 256, 0, stream>>>(
      Sbf, vbf, h_t, nullptr, nullptr, 1.f, 1024, 512, 1024,
      1048576, 524288, 524288, 0, lsum);
  // out = wp . h^T + bp + x
  gemm_bt<EPI_RES_F32><<<dim3(8, 4, 16), 256, 0, stream>>>(
      wbf + 786432, h_t, d_out, bp, x, 1.f, 512, 1024, 512,
      0, 524288, 524288, 524288, nullptr);
}